// Round 1
// 101.815 us; speedup vs baseline: 1.0086x; 1.0086x over previous
//
#include <hip/hip_runtime.h>

#define MK 4096
#define BK 128

typedef int v4i __attribute__((ext_vector_type(4)));
typedef int v16i __attribute__((ext_vector_type(16)));

#define MFMA32(a, b, c) __builtin_amdgcn_mfma_i32_32x32x32_i8(a, b, c, 0, 0, 0)

#define GLOAD_LDS16(gp, lp) \
  __builtin_amdgcn_global_load_lds((const __attribute__((address_space(1))) void*)(gp), \
                                   (__attribute__((address_space(3))) void*)(lp), 16, 0, 0)
#define GLOAD_LDS4(gp, lp) \
  __builtin_amdgcn_global_load_lds((const __attribute__((address_space(1))) void*)(gp), \
                                   (__attribute__((address_space(3))) void*)(lp), 4, 0, 0)

#define SB() __builtin_amdgcn_sched_barrier(0)
#define BARRIER() __builtin_amdgcn_s_barrier()
#define WAIT_VM6() asm volatile("s_waitcnt vmcnt(6)" ::: "memory")
#define WAIT_VM2() asm volatile("s_waitcnt vmcnt(2)" ::: "memory")
#define WAIT_VM0() asm volatile("s_waitcnt vmcnt(0)" ::: "memory")
#define NOWAIT() ((void)0)

// ---------------- convert mat1 int32 -> int8 (same layout) ----------------
__global__ __launch_bounds__(256) void cvtA_kernel(const int* __restrict__ src,
                                                   char* __restrict__ dst, int n4) {
  int idx = blockIdx.x * blockDim.x + threadIdx.x;
  int stride = gridDim.x * blockDim.x;
  for (int i = idx; i < n4; i += stride) {
    int4 v = ((const int4*)src)[i];
    char4 c;
    c.x = (char)v.x; c.y = (char)v.y; c.z = (char)v.z; c.w = (char)v.w;
    ((char4*)dst)[i] = c;
  }
}

// ------------- convert+transpose mat2 [K][N] int32 -> [N][K] int8 ----------
__global__ __launch_bounds__(256) void cvtB_kernel(const int* __restrict__ src,
                                                   char* __restrict__ dst) {
  __shared__ char tile[64][68];
  const int t = threadIdx.x;
  const int n0 = blockIdx.x * 64, k0 = blockIdx.y * 64;
#pragma unroll
  for (int r = 0; r < 16; ++r) {
    int k = k0 + r * 4 + (t >> 6);
    int n = n0 + (t & 63);
    tile[t & 63][r * 4 + (t >> 6)] = (char)src[(size_t)k * MK + n];
  }
  __syncthreads();
#pragma unroll
  for (int w = 0; w < 4; ++w) {
    int nl = w * 16 + (t >> 4);
    int kl = (t & 15) * 4;
    char4 c = *(const char4*)&tile[nl][kl];
    *(char4*)(dst + (size_t)(n0 + nl) * MK + k0 + kl) = c;
  }
}

// ---------------- i8 MFMA GEMM, 256x256 tile, 32x32x32 MFMA ----------------
// R6: inp L3-prefetch. The epilogue's 128 MB HBM burst (inp read + out write)
// was a ~25us MFMA-idle tail (1 block/CU, nothing co-resident to hide it).
// Main loop HBM is ~0.8 TB/s, so we warm inp into L2/L3 during the K-loop:
// 2x global_load_lds(width=4) per wave per half into a dead 256B LDS scratch
// slot (pure cache-warm; data never read from LDS). Covers 4 rows of the
// 256x256 inp tile per half x 64 pf-steps (prologue + 63 HALFs) = 256 rows.
// FIFO discipline updated: each half = 6 VMEM ops (2 pf + 4 stage); half-end
// wait = vmcnt(6) (leave current half's 6, drain the half read 2 regions
// later -- same invariant as R5's vmcnt(4)); tile-31 h0 wait = vmcnt(2)
// (drain half-61 staging, leave half-62's pf). Epilogue inp loads are plain
// (not nontemporal) so they hit the warmed cache.
// LDS half layout (16 KiB): [blk:8][kk:2][r15:16][slot:4][16B],
// slot = (2*khalf + (row>>4)) ^ ((row&15)>>1 & 3)  (R4-verified 0-conflict).
__global__ __launch_bounds__(512, 2) void gemm_i8_kernel(const char* __restrict__ A8,
                                                         const char* __restrict__ B8T,
                                                         const int* __restrict__ inp,
                                                         float* __restrict__ out) {
  extern __shared__ char lds[];
  const int tid = threadIdx.x;
  const int wg = blockIdx.x;
  const int wgs = (wg & 7) * 32 + (wg >> 3);  // XCD-aware, bijective (256%8==0)
  const int m0 = (wgs >> 4) << 8;
  const int n0 = (wgs & 15) << 8;

  const int lane = tid & 63, wid = tid >> 6;
  const int wr = wid >> 2, wc = wid & 3;
  const int rl = lane & 31;
  const int khalf = lane >> 5;

  // per-lane LDS read base: R2/R4's measured-0-conflict pattern
  const int r15 = lane & 15;
  const int slotr = (lane >> 4) ^ ((r15 >> 1) & 3);
  const char* pAr = lds + wr * 8192 + r15 * 64 + slotr * 16;
  const char* pBr = lds + 65536 + wc * 4096 + r15 * 64 + slotr * 16;

  // staging decode: thread t feeds LDS chunk idx=t (and idx+512 = +4 blks)
  const int sblk = tid >> 7;
  const int skk = (tid >> 6) & 1;
  const int sr15 = (tid >> 2) & 15;
  const int sslot = tid & 3;
  const int sx = sslot ^ ((sr15 >> 1) & 3);
  const int srow = sblk * 32 + (sx & 1) * 16 + sr15;
  const int skb = skk * 32 + (sx >> 1) * 16;
  const char* pA = A8 + (size_t)(m0 + srow) * MK + skb;
  const char* pB = B8T + (size_t)(n0 + srow) * MK + skb;
  char* ldsw = lds + (tid & ~63) * 16;  // wave-uniform dest base (+hw lane*16)

  // inp prefetch: pf-step s covers tile rows 4s..4s+3. op1: rows 4s+(tid>>8),
  // op2: rows 4s+2+(tid>>8); cols = tid&255. 64 lanes = 256B contiguous.
  const int* pfp = inp + (size_t)(m0 + (tid >> 8)) * MK + (n0 + (tid & 255));
  char* pfs = lds + 131072;  // dead scratch, wave-uniform base

#define PF_INP() do {                                                             \
    GLOAD_LDS4(pfp, pfs);                                                         \
    GLOAD_LDS4(pfp + 2 * MK, pfs);                                                \
    pfp += 4 * MK;                                                                \
  } while (0)

#define STAGE_A_(NB_, H_, TN_) do {                                               \
    const char* s_ = pA + (TN_)*BK + (H_)*64;                                     \
    GLOAD_LDS16(s_,                    ldsw + ((NB_)*32768 + (H_)*16384));        \
    GLOAD_LDS16(s_ + (size_t)128 * MK, ldsw + ((NB_)*32768 + (H_)*16384 + 8192)); \
  } while (0)
#define STAGE_B_(NB_, H_, TN_) do {                                               \
    const char* s_ = pB + (TN_)*BK + (H_)*64;                                     \
    GLOAD_LDS16(s_,                    ldsw + (65536 + (NB_)*32768 + (H_)*16384)); \
    GLOAD_LDS16(s_ + (size_t)128 * MK, ldsw + (65536 + (NB_)*32768 + (H_)*16384 + 8192)); \
  } while (0)

#define AOFF(B_, KK_, MB_) ((B_)*32768 + ((KK_) >> 1) * 16384 + (MB_)*2048 + ((KK_)&1) * 1024)
#define BOFF(B_, KK_, NB_) ((B_)*32768 + ((KK_) >> 1) * 16384 + (NB_)*2048 + ((KK_)&1) * 1024)

// one phase = one kk-step: 6 ds_read_b128 + optional stage-pair + 8 MFMA.
// No barriers here: compiler inserts lgkmcnt; waves free-run within the half.
#define PH(B_, KK_, STO_) do {                                                    \
    af0 = *(const v4i*)(pAr + AOFF(B_, KK_, 0));                                  \
    af1 = *(const v4i*)(pAr + AOFF(B_, KK_, 1));                                  \
    af2 = *(const v4i*)(pAr + AOFF(B_, KK_, 2));                                  \
    af3 = *(const v4i*)(pAr + AOFF(B_, KK_, 3));                                  \
    bf0 = *(const v4i*)(pBr + BOFF(B_, KK_, 0));                                  \
    bf1 = *(const v4i*)(pBr + BOFF(B_, KK_, 1));                                  \
    STO_;                                                                         \
    __builtin_amdgcn_s_setprio(1);                                                \
    acc[0][0] = MFMA32(af0, bf0, acc[0][0]); acc[0][1] = MFMA32(af0, bf1, acc[0][1]); \
    acc[1][0] = MFMA32(af1, bf0, acc[1][0]); acc[1][1] = MFMA32(af1, bf1, acc[1][1]); \
    acc[2][0] = MFMA32(af2, bf0, acc[2][0]); acc[2][1] = MFMA32(af2, bf1, acc[2][1]); \
    acc[3][0] = MFMA32(af3, bf0, acc[3][0]); acc[3][1] = MFMA32(af3, bf1, acc[3][1]); \
    __builtin_amdgcn_s_setprio(0);                                                \
  } while (0)

// half-tile region: pf pair + 2 phases, then vmcnt+barrier (the ONLY sync per
// half). FIFO invariant: at each half-end, queue = 12 outstanding max;
// vmcnt(6) leaves the current half's 6 ops (2 pf + 4 stage), draining the
// staging the NEXT-next region reads.
#define HALF(B_, H_, TN_, DOST_, VMW_) do {                                       \
    PF_INP();                                                                     \
    if (DOST_) { PH(B_, 2*(H_), STAGE_A_((B_) ^ 1, H_, TN_));                     \
                 PH(B_, 2*(H_) + 1, STAGE_B_((B_) ^ 1, H_, TN_)); }               \
    else       { PH(B_, 2*(H_), NOWAIT()); PH(B_, 2*(H_) + 1, NOWAIT()); }        \
    SB(); VMW_; BARRIER(); SB();                                                  \
  } while (0)

  v16i acc[4][2];
#pragma unroll
  for (int m = 0; m < 4; ++m)
#pragma unroll
    for (int n = 0; n < 2; ++n)
#pragma unroll
      for (int i = 0; i < 16; ++i) acc[m][n][i] = 0;
  v4i af0, af1, af2, af3, bf0, bf1;

  // prologue: stage tile 0 -> buf0 (8 loads) + pf step 0, drain h0, sync.
  // vmcnt(6) leaves [t0h1 stage (4), pf (2)], drains t0h0's 4.
  STAGE_A_(0, 0, 0); STAGE_B_(0, 0, 0); STAGE_A_(0, 1, 0); STAGE_B_(0, 1, 0);
  PF_INP();
  WAIT_VM6(); BARRIER(); SB();

#pragma unroll 1
  for (int it = 0; it < 15; ++it) {
    HALF(0, 0, 2 * it + 1, 1, WAIT_VM6());
    HALF(0, 1, 2 * it + 1, 1, WAIT_VM6());
    HALF(1, 0, 2 * it + 2, 1, WAIT_VM6());
    HALF(1, 1, 2 * it + 2, 1, WAIT_VM6());
  }
  HALF(0, 0, 31, 1, WAIT_VM6());
  HALF(0, 1, 31, 1, WAIT_VM6());
  // tile 31 h0: no staging, pf only (2 ops). vmcnt(2) drains half-61's
  // staging (read by the final inline half) and half-61's pf; leaves pf62.
  HALF(1, 0, 0, 0, WAIT_VM2());
  PH(1, 2, NOWAIT()); PH(1, 3, NOWAIT());  // last half, no sync needed after

  // epilogue: 32x32 C/D layout col=lane&31, row=(reg&3)+8*(reg>>2)+4*khalf.
  // inp loads are PLAIN (hit the L2/L3 lines warmed by PF_INP); stores stay
  // nontemporal (no reuse).
#pragma unroll
  for (int mb = 0; mb < 4; ++mb) {
#pragma unroll
    for (int nb = 0; nb < 2; ++nb) {
      const int col = n0 + wc * 64 + nb * 32 + rl;
      const int row0 = m0 + wr * 128 + mb * 32 + 4 * khalf;
#pragma unroll
      for (int r = 0; r < 16; ++r) {
        const int row = row0 + (r & 3) + 8 * (r >> 2);
        const size_t idx = (size_t)row * MK + col;
        const int v = acc[mb][nb][r] + inp[idx];
        __builtin_nontemporal_store((float)v, out + idx);
      }
    }
  }
}

// ---------------- fallback (only if ws too small): naive tiled int32 -------
__global__ void fallback_kernel(const int* __restrict__ mat1, const int* __restrict__ mat2,
                                const int* __restrict__ inp, float* __restrict__ out) {
  __shared__ int As[16][16], Bs[16][17];
  int tx = threadIdx.x, ty = threadIdx.y;
  int row = blockIdx.y * 16 + ty, col = blockIdx.x * 16 + tx;
  int acc = 0;
  for (int kt = 0; kt < MK / 16; ++kt) {
    As[ty][tx] = mat1[(size_t)row * MK + kt * 16 + tx];
    Bs[ty][tx] = mat2[(size_t)(kt * 16 + ty) * MK + col];
    __syncthreads();
#pragma unroll
    for (int k = 0; k < 16; ++k) acc += As[ty][k] * Bs[k][tx];
    __syncthreads();
  }
  size_t idx = (size_t)row * MK + col;
  out[idx] = (float)(acc + inp[idx]);
}

extern "C" void kernel_launch(void* const* d_in, const int* in_sizes, int n_in,
                              void* d_out, int out_size, void* d_ws, size_t ws_size,
                              hipStream_t stream) {
  const int* inp = (const int*)d_in[0];
  const int* mat1 = (const int*)d_in[1];
  const int* mat2 = (const int*)d_in[2];
  float* out = (float*)d_out;

  const size_t need = 2 * (size_t)MK * MK;
  if (ws_size >= need) {
    char* A8 = (char*)d_ws;
    char* B8T = A8 + (size_t)MK * MK;
    cvtA_kernel<<<2048, 256, 0, stream>>>(mat1, A8, MK * MK / 4);
    dim3 gb(MK / 64, MK / 64);
    cvtB_kernel<<<gb, 256, 0, stream>>>(mat2, B8T);
    (void)hipFuncSetAttribute((const void*)gemm_i8_kernel,
                              hipFuncAttributeMaxDynamicSharedMemorySize, 131328);
    gemm_i8_kernel<<<256, 512, 131328, stream>>>(A8, B8T, inp, out);
  } else {
    dim3 blk(16, 16), grd(MK / 16, MK / 16);
    fallback_kernel<<<grd, blk, 0, stream>>>(mat1, mat2, inp, out);
  }
}